// Round 1
// baseline (5641.640 us; speedup 1.0000x reference)
//
#include <hip/hip_runtime.h>

#define NN 100000
#define NE 3200000
#define D  128

// ---------------- degree / norm ----------------
__global__ void k_init_deg(float* __restrict__ deg) {
    int i = blockIdx.x * 256 + threadIdx.x;
    if (i < NN) deg[i] = 1.0f;               // self-loop
}

__global__ void k_count(const int* __restrict__ dst, float* __restrict__ deg) {
    int i = blockIdx.x * 256 + threadIdx.x;
    if (i < NE) atomicAdd(&deg[dst[i]], 1.0f);
}

__global__ void k_rsqrt(float* __restrict__ deg) {
    int i = blockIdx.x * 256 + threadIdx.x;
    if (i < NN) deg[i] = rsqrtf(deg[i]);     // deg >= 1 always
}

// ---------------- GEMM: h = x @ W  (fp32, vector ALU) ----------------
// 64 rows/block, 256 threads, per-thread 8x4 register tile.
// W fully in LDS (64KB), x tile transposed in LDS for float4 fragment loads.
__global__ __launch_bounds__(256) void k_gemm(const float* __restrict__ x,
                                              const float* __restrict__ W,
                                              float* __restrict__ h, int nrows) {
    __shared__ __align__(16) float Ws[128 * 128];      // [k][c]
    __shared__ __align__(16) float xs[128][72];        // [k][r], pad 72
    const int t = threadIdx.x;
    const int row0 = blockIdx.x * 64;

    // load W (16384 floats / 256 threads = 16 float4 each... 4 each x 16 iters)
    for (int i = t * 4; i < 128 * 128; i += 256 * 4)
        *(float4*)&Ws[i] = *(const float4*)&W[i];

    // load x tile transposed
    for (int i = t; i < 64 * 32; i += 256) {
        int r  = i >> 5;             // 0..63
        int k4 = (i & 31) * 4;       // 0..124
        int row = row0 + r;
        float4 v = make_float4(0.f, 0.f, 0.f, 0.f);
        if (row < nrows) v = *(const float4*)&x[(size_t)row * D + k4];
        xs[k4 + 0][r] = v.x; xs[k4 + 1][r] = v.y;
        xs[k4 + 2][r] = v.z; xs[k4 + 3][r] = v.w;
    }
    __syncthreads();

    const int rr = (t >> 5) * 8;     // 8 row-groups of 8
    const int cc = (t & 31) * 4;     // 32 col-groups of 4
    float acc[8][4] = {};
    for (int k = 0; k < 128; ++k) {
        float4 b  = *(float4*)&Ws[k * 128 + cc];
        float4 a0 = *(float4*)&xs[k][rr];
        float4 a1 = *(float4*)&xs[k][rr + 4];
        float a[8] = {a0.x, a0.y, a0.z, a0.w, a1.x, a1.y, a1.z, a1.w};
#pragma unroll
        for (int r = 0; r < 8; ++r)
#pragma unroll
            for (int c = 0; c < 4; ++c)
                acc[r][c] = fmaf(a[r], (&b.x)[c], acc[r][c]);
    }

#pragma unroll
    for (int r = 0; r < 8; ++r) {
        int row = row0 + rr + r;
        if (row < nrows)
            *(float4*)&h[(size_t)row * D + cc] =
                make_float4(acc[r][0], acc[r][1], acc[r][2], acc[r][3]);
    }
}

// ---------------- self-loop init: out = h * dinv^2 ----------------
__global__ void k_self(const float* __restrict__ h, const float* __restrict__ dinv,
                       float* __restrict__ out) {
    int i = blockIdx.x * 256 + threadIdx.x;   // over NN*32
    if (i >= NN * 32) return;
    int node = i >> 5;
    int c4 = (i & 31) * 4;
    float w = dinv[node]; w *= w;
    float4 v = *(const float4*)&h[(size_t)node * D + c4];
    v.x *= w; v.y *= w; v.z *= w; v.w *= w;
    *(float4*)&out[(size_t)node * D + c4] = v;
}

// ---------------- edge scatter: out[dst] += h[src] * norm ----------------
__global__ void k_scatter(const int* __restrict__ src, const int* __restrict__ dst,
                          const float* __restrict__ h, const float* __restrict__ dinv,
                          float* __restrict__ out) {
    unsigned int i = blockIdx.x * 256 + threadIdx.x;  // over NE*32 = 102.4M
    if (i >= (unsigned int)NE * 32u) return;
    int e  = i >> 5;
    int c4 = (i & 31) * 4;
    int s = src[e], d = dst[e];
    float w = dinv[s] * dinv[d];
    float4 v = *(const float4*)&h[(size_t)s * D + c4];
    float* o = &out[(size_t)d * D + c4];
    atomicAdd(o + 0, v.x * w);
    atomicAdd(o + 1, v.y * w);
    atomicAdd(o + 2, v.z * w);
    atomicAdd(o + 3, v.w * w);
}

// ---------------- epilogue: out = relu(out + b) ----------------
__global__ void k_finish(float* __restrict__ out, const float* __restrict__ b) {
    int i = blockIdx.x * 256 + threadIdx.x;   // over NN*32
    if (i >= NN * 32) return;
    int c4 = (i & 31) * 4;
    float4 v = *(float4*)&out[(size_t)i * 4];
    float4 bb = *(const float4*)&b[c4];
    v.x = fmaxf(v.x + bb.x, 0.f);
    v.y = fmaxf(v.y + bb.y, 0.f);
    v.z = fmaxf(v.z + bb.z, 0.f);
    v.w = fmaxf(v.w + bb.w, 0.f);
    *(float4*)&out[(size_t)i * 4] = v;
}

extern "C" void kernel_launch(void* const* d_in, const int* in_sizes, int n_in,
                              void* d_out, int out_size, void* d_ws, size_t ws_size,
                              hipStream_t stream) {
    const float* x  = (const float*)d_in[0];      // [NN, 128]
    const int*   ei = (const int*)d_in[1];        // [2, NE]
    const float* W  = (const float*)d_in[2];      // [128, 128]
    const float* b  = (const float*)d_in[3];      // [128]
    float* out = (float*)d_out;                   // [NN, 128]

    float* h    = (float*)d_ws;                   // NN*128 floats = 51.2 MB
    float* dinv = h + (size_t)NN * D;             // NN floats

    const int* src = ei;
    const int* dst = ei + NE;

    k_init_deg<<<(NN + 255) / 256, 256, 0, stream>>>(dinv);
    k_count<<<(NE + 255) / 256, 256, 0, stream>>>(dst, dinv);
    k_rsqrt<<<(NN + 255) / 256, 256, 0, stream>>>(dinv);
    k_gemm<<<(NN + 63) / 64, 256, 0, stream>>>(x, W, h, NN);
    k_self<<<(NN * 32 + 255) / 256, 256, 0, stream>>>(h, dinv, out);
    k_scatter<<<(NE * 32 + 255) / 256, 256, 0, stream>>>(src, dst, h, dinv, out);
    k_finish<<<(NN * 32 + 255) / 256, 256, 0, stream>>>(out, b);
}

// Round 2
// 763.020 us; speedup vs baseline: 7.3938x; 7.3938x over previous
//
#include <hip/hip_runtime.h>

#define NN 100000
#define NE 3200000
#define D  128
#define NB ((NN + 255) / 256)   // 391 scan blocks

// ---------------- histogram of dst ----------------
__global__ void k_zero(int* __restrict__ cnt) {
    int i = blockIdx.x * 256 + threadIdx.x;
    if (i < NN) cnt[i] = 0;
}

__global__ void k_count(const int* __restrict__ dst, int* __restrict__ cnt) {
    int i = blockIdx.x * 256 + threadIdx.x;
    if (i < NE) atomicAdd(&cnt[dst[i]], 1);
}

// ---------------- exclusive scan (3-kernel, 100K elems) ----------------
__global__ void k_scan1(const int* __restrict__ cnt, int* __restrict__ offs,
                        int* __restrict__ bsum, float* __restrict__ dinv) {
    __shared__ int s[256];
    int i = blockIdx.x * 256 + threadIdx.x;
    int v = (i < NN) ? cnt[i] : 0;
    if (i < NN) dinv[i] = rsqrtf(1.0f + (float)v);   // deg incl. self-loop
    s[threadIdx.x] = v;
    __syncthreads();
    for (int d = 1; d < 256; d <<= 1) {
        int t = (threadIdx.x >= d) ? s[threadIdx.x - d] : 0;
        __syncthreads();
        s[threadIdx.x] += t;
        __syncthreads();
    }
    if (i < NN) offs[i] = s[threadIdx.x] - v;        // exclusive within block
    if (threadIdx.x == 255) bsum[blockIdx.x] = s[255];
}

__global__ void k_scan2(int* __restrict__ bsum) {
    __shared__ int s[512];
    int v = (threadIdx.x < NB) ? bsum[threadIdx.x] : 0;
    s[threadIdx.x] = v;
    __syncthreads();
    for (int d = 1; d < 512; d <<= 1) {
        int t = (threadIdx.x >= d) ? s[threadIdx.x - d] : 0;
        __syncthreads();
        s[threadIdx.x] += t;
        __syncthreads();
    }
    if (threadIdx.x < NB) bsum[threadIdx.x] = s[threadIdx.x] - v;  // exclusive
}

__global__ void k_scan3(int* __restrict__ offs, const int* __restrict__ bsum,
                        int* __restrict__ cursor) {
    int i = blockIdx.x * 256 + threadIdx.x;
    if (i < NN) {
        int o = offs[i] + bsum[blockIdx.x];
        offs[i] = o;
        cursor[i] = o;
    }
    if (i == 0) offs[NN] = NE;
}

// ---------------- bucket fill: CSR by dst ----------------
__global__ void k_fill(const int* __restrict__ src, const int* __restrict__ dst,
                       int* __restrict__ cursor, int* __restrict__ csr) {
    int e = blockIdx.x * 256 + threadIdx.x;
    if (e < NE) {
        int p = atomicAdd(&cursor[dst[e]], 1);
        csr[p] = src[e];
    }
}

// ---------------- GEMM: h = x @ W  (fp32, vector ALU) ----------------
__global__ __launch_bounds__(256) void k_gemm(const float* __restrict__ x,
                                              const float* __restrict__ W,
                                              float* __restrict__ h, int nrows) {
    __shared__ __align__(16) float Ws[128 * 128];
    __shared__ __align__(16) float xs[128][72];
    const int t = threadIdx.x;
    const int row0 = blockIdx.x * 64;

    for (int i = t * 4; i < 128 * 128; i += 256 * 4)
        *(float4*)&Ws[i] = *(const float4*)&W[i];

    for (int i = t; i < 64 * 32; i += 256) {
        int r  = i >> 5;
        int k4 = (i & 31) * 4;
        int row = row0 + r;
        float4 v = make_float4(0.f, 0.f, 0.f, 0.f);
        if (row < nrows) v = *(const float4*)&x[(size_t)row * D + k4];
        xs[k4 + 0][r] = v.x; xs[k4 + 1][r] = v.y;
        xs[k4 + 2][r] = v.z; xs[k4 + 3][r] = v.w;
    }
    __syncthreads();

    const int rr = (t >> 5) * 8;
    const int cc = (t & 31) * 4;
    float acc[8][4] = {};
    for (int k = 0; k < 128; ++k) {
        float4 bv = *(float4*)&Ws[k * 128 + cc];
        float4 a0 = *(float4*)&xs[k][rr];
        float4 a1 = *(float4*)&xs[k][rr + 4];
        float a[8] = {a0.x, a0.y, a0.z, a0.w, a1.x, a1.y, a1.z, a1.w};
#pragma unroll
        for (int r = 0; r < 8; ++r)
#pragma unroll
            for (int c = 0; c < 4; ++c)
                acc[r][c] = fmaf(a[r], (&bv.x)[c], acc[r][c]);
    }

#pragma unroll
    for (int r = 0; r < 8; ++r) {
        int row = row0 + rr + r;
        if (row < nrows)
            *(float4*)&h[(size_t)row * D + cc] =
                make_float4(acc[r][0], acc[r][1], acc[r][2], acc[r][3]);
    }
}

// ---------------- fused aggregate: wave per node ----------------
// acc = dinv[n]^2 * h[n] + sum_{e in CSR[n]} dinv[src]*dinv[n]*h[src]
// out = relu(acc + b)
__global__ __launch_bounds__(256) void k_agg(const float* __restrict__ h,
                                             const float* __restrict__ dinv,
                                             const int* __restrict__ offs,
                                             const int* __restrict__ csr,
                                             const float* __restrict__ b,
                                             float* __restrict__ out) {
    const int wave = threadIdx.x >> 6;
    const int lane = threadIdx.x & 63;
    const int node = blockIdx.x * 4 + wave;
    if (node >= NN) return;
    const int c = lane * 2;

    const float dd = dinv[node];
    float2 acc = *(const float2*)&h[(size_t)node * D + c];
    acc.x *= dd * dd;
    acc.y *= dd * dd;

    const int j0 = offs[node], j1 = offs[node + 1];
    int j = j0;
    for (; j + 1 < j1; j += 2) {             // 2-edge unroll for load ILP
        int s0 = csr[j], s1 = csr[j + 1];
        float w0 = dinv[s0] * dd;
        float w1 = dinv[s1] * dd;
        float2 v0 = *(const float2*)&h[(size_t)s0 * D + c];
        float2 v1 = *(const float2*)&h[(size_t)s1 * D + c];
        acc.x = fmaf(v0.x, w0, acc.x);
        acc.y = fmaf(v0.y, w0, acc.y);
        acc.x = fmaf(v1.x, w1, acc.x);
        acc.y = fmaf(v1.y, w1, acc.y);
    }
    if (j < j1) {
        int s0 = csr[j];
        float w0 = dinv[s0] * dd;
        float2 v0 = *(const float2*)&h[(size_t)s0 * D + c];
        acc.x = fmaf(v0.x, w0, acc.x);
        acc.y = fmaf(v0.y, w0, acc.y);
    }

    float2 bb = *(const float2*)&b[c];
    acc.x = fmaxf(acc.x + bb.x, 0.f);
    acc.y = fmaxf(acc.y + bb.y, 0.f);
    *(float2*)&out[(size_t)node * D + c] = acc;
}

extern "C" void kernel_launch(void* const* d_in, const int* in_sizes, int n_in,
                              void* d_out, int out_size, void* d_ws, size_t ws_size,
                              hipStream_t stream) {
    const float* x  = (const float*)d_in[0];      // [NN, 128]
    const int*   ei = (const int*)d_in[1];        // [2, NE]
    const float* W  = (const float*)d_in[2];      // [128, 128]
    const float* b  = (const float*)d_in[3];      // [128]
    float* out = (float*)d_out;                   // [NN, 128]

    // workspace layout
    float* h      = (float*)d_ws;                 // NN*D floats   (51.2 MB)
    float* dinv   = h + (size_t)NN * D;           // NN floats
    int*   cnt    = (int*)(dinv + NN);            // NN ints
    int*   offs   = cnt + NN;                     // NN+1 ints
    int*   bsum   = offs + NN + 1;                // NB ints
    int*   cursor = bsum + NB + 1;                // NN ints
    int*   csr    = cursor + NN;                  // NE ints       (12.8 MB)

    const int* src = ei;
    const int* dst = ei + NE;

    k_zero <<<NB, 256, 0, stream>>>(cnt);
    k_count<<<(NE + 255) / 256, 256, 0, stream>>>(dst, cnt);
    k_scan1<<<NB, 256, 0, stream>>>(cnt, offs, bsum, dinv);
    k_scan2<<<1, 512, 0, stream>>>(bsum);
    k_scan3<<<NB, 256, 0, stream>>>(offs, bsum, cursor);
    k_fill <<<(NE + 255) / 256, 256, 0, stream>>>(src, dst, cursor, csr);
    k_gemm <<<(NN + 63) / 64, 256, 0, stream>>>(x, W, h, NN);
    k_agg  <<<(NN + 3) / 4, 256, 0, stream>>>(h, dinv, offs, csr, b, out);
}